// Round 1
// baseline (861.029 us; speedup 1.0000x reference)
//
#include <hip/hip_runtime.h>

// ---------- types ----------
typedef __bf16 bf16x8 __attribute__((ext_vector_type(8)));
typedef float f32x4 __attribute__((ext_vector_type(4)));
typedef unsigned short u16x8 __attribute__((ext_vector_type(8)));

__device__ __forceinline__ unsigned short f2bf(float f) {
  union { float f; unsigned u; } v; v.f = f;
  unsigned r = (v.u + 0x7fffu + ((v.u >> 16) & 1u)) >> 16;
  return (unsigned short)r;
}
__device__ __forceinline__ float bf2f(unsigned short s) {
  union { unsigned u; float f; } v; v.u = ((unsigned)s) << 16;
  return v.f;
}

#define GLD16(g, l)                                                        \
  __builtin_amdgcn_global_load_lds(                                        \
      (const __attribute__((address_space(1))) void*)(g),                  \
      (__attribute__((address_space(3))) void*)(l), 16, 0, 0)

// ---------- f32 -> bf16 cast ----------
__global__ __launch_bounds__(256) void cast_bf16_kernel(
    const float* __restrict__ in, unsigned short* __restrict__ out, int n4) {
  int i = blockIdx.x * 256 + threadIdx.x;
  int stride = gridDim.x * 256;
  for (; i < n4; i += stride) {
    float4 f = reinterpret_cast<const float4*>(in)[i];
    ushort4 s;
    s.x = f2bf(f.x); s.y = f2bf(f.y); s.z = f2bf(f.z); s.w = f2bf(f.w);
    reinterpret_cast<ushort4*>(out)[i] = s;
  }
}

// ---------- bf16 NT GEMM: C[m,n] = sum_k A[m,k]*B[n,k] + bias[n] ----------
// A:[M,K] bf16 row-major, B:[N,K] bf16 row-major. 128x128 tile, BK=64,
// 4 waves in 2x2, each 64x64 (4x4 MFMA 16x16x32 frags).
template <int F32OUT>
__global__ __launch_bounds__(256) void gemm_bt(
    const unsigned short* __restrict__ A, const unsigned short* __restrict__ B,
    const float* __restrict__ bias, void* __restrict__ Cp, int M, int N, int K) {
  __shared__ unsigned short As[128 * 64];
  __shared__ unsigned short Bs[128 * 64];
  const int tid = threadIdx.x;
  const int lane = tid & 63;
  const int wid = tid >> 6;
  const int wr = wid >> 1, wc = wid & 1;
  const int l15 = lane & 15, l4 = lane >> 4;
  const int row0 = blockIdx.y * 128, col0 = blockIdx.x * 128;

  f32x4 acc[4][4] = {};

  const int srow = lane >> 3;        // row within an 8-row chunk
  const int scol = (lane & 7) * 8;   // elem col within BK

  for (int kt = 0; kt < K; kt += 64) {
    __syncthreads();
#pragma unroll
    for (int i = 0; i < 4; ++i) {
      int c = wid * 4 + i;  // wave-uniform chunk id
      GLD16(A + (size_t)(row0 + c * 8 + srow) * K + kt + scol, &As[c * 512]);
      GLD16(B + (size_t)(col0 + c * 8 + srow) * K + kt + scol, &Bs[c * 512]);
    }
    __syncthreads();
#pragma unroll
    for (int ks = 0; ks < 2; ++ks) {
      const int ko = ks * 32 + l4 * 8;
      bf16x8 af[4], bfr[4];
#pragma unroll
      for (int mi = 0; mi < 4; ++mi)
        af[mi] = *(const bf16x8*)&As[(wr * 64 + mi * 16 + l15) * 64 + ko];
#pragma unroll
      for (int ni = 0; ni < 4; ++ni)
        bfr[ni] = *(const bf16x8*)&Bs[(wc * 64 + ni * 16 + l15) * 64 + ko];
#pragma unroll
      for (int mi = 0; mi < 4; ++mi)
#pragma unroll
        for (int ni = 0; ni < 4; ++ni)
          acc[mi][ni] = __builtin_amdgcn_mfma_f32_16x16x32_bf16(
              af[mi], bfr[ni], acc[mi][ni], 0, 0, 0);
    }
  }

#pragma unroll
  for (int mi = 0; mi < 4; ++mi)
#pragma unroll
    for (int ni = 0; ni < 4; ++ni)
#pragma unroll
      for (int r = 0; r < 4; ++r) {
        int row = row0 + wr * 64 + mi * 16 + l4 * 4 + r;
        int col = col0 + wc * 64 + ni * 16 + l15;
        float v = acc[mi][ni][r] + bias[col];
        if (F32OUT)
          ((float*)Cp)[(size_t)row * N + col] = v;
        else
          ((unsigned short*)Cp)[(size_t)row * N + col] = f2bf(v);
      }
}

// ---------- in-place RMS norm over rows of 2048 (bf16) ----------
__global__ __launch_bounds__(256) void rmsnorm_kernel(
    unsigned short* __restrict__ T, const float* __restrict__ w) {
  const int row = blockIdx.x;
  const int tid = threadIdx.x;
  unsigned short* p = T + (size_t)row * 2048;
  u16x8 v = *(const u16x8*)&p[tid * 8];
  float f[8];
  float ss = 0.f;
#pragma unroll
  for (int j = 0; j < 8; ++j) { f[j] = bf2f(v[j]); ss += f[j] * f[j]; }
#pragma unroll
  for (int m = 1; m < 64; m <<= 1) ss += __shfl_xor(ss, m, 64);
  __shared__ float red[4];
  const int wid = tid >> 6, lane = tid & 63;
  if (lane == 0) red[wid] = ss;
  __syncthreads();
  float tot = red[0] + red[1] + red[2] + red[3];
  float rs = rsqrtf(tot * (1.0f / 2048.0f) + 1e-6f);
  u16x8 o;
#pragma unroll
  for (int j = 0; j < 8; ++j) o[j] = f2bf(f[j] * rs * w[tid * 8 + j]);
  *(u16x8*)&p[tid * 8] = o;
}

// ---------- flash attention: 4096 q x 4096 k, H=32 heads, DH=64 ----------
// grid (32 qtiles, 32 heads), 256 threads. QBLK=128 (32 q/wave), KBLK=64.
__global__ __launch_bounds__(256) void flash_attn(
    const unsigned short* __restrict__ Q, const unsigned short* __restrict__ K,
    const unsigned short* __restrict__ V, unsigned short* __restrict__ O) {
  __shared__ unsigned short Ks[64 * 64];      // [key][dh]
  __shared__ unsigned short Vs[64 * 64];      // transposed: [dh][key]
  __shared__ unsigned short Ps[4][32 * 64];   // per-wave P staging
  const int h = blockIdx.y;
  const int q0 = blockIdx.x * 128;
  const int tid = threadIdx.x, lane = tid & 63, wid = tid >> 6;
  const int l15 = lane & 15, l4 = lane >> 4;

  // Q fragments held in registers for the whole kernel
  bf16x8 qf[2][2];
#pragma unroll
  for (int mi = 0; mi < 2; ++mi)
#pragma unroll
    for (int ks = 0; ks < 2; ++ks) {
      int qrow = q0 + wid * 32 + mi * 16 + l15;
      qf[mi][ks] = *(const bf16x8*)&Q[(size_t)qrow * 2048 + h * 64 + ks * 32 + l4 * 8];
    }

  float m_s[2][4], l_s[2][4];
  f32x4 o_acc[2][4] = {};
#pragma unroll
  for (int mi = 0; mi < 2; ++mi)
#pragma unroll
    for (int r = 0; r < 4; ++r) { m_s[mi][r] = -1e30f; l_s[mi][r] = 0.f; }

  for (int kt = 0; kt < 4096; kt += 64) {
    __syncthreads();
    // stage K tile linearly via async global->LDS
#pragma unroll
    for (int i = 0; i < 2; ++i) {
      int c = wid * 2 + i;
      GLD16(K + (size_t)(kt + c * 8 + (lane >> 3)) * 2048 + h * 64 + (lane & 7) * 8,
            &Ks[c * 512]);
    }
    // stage V transposed via registers
#pragma unroll
    for (int i = 0; i < 2; ++i) {
      int c2 = i * 256 + tid;
      int key = c2 >> 3, d0 = (c2 & 7) * 8;
      u16x8 vv = *(const u16x8*)&V[(size_t)(kt + key) * 2048 + h * 64 + d0];
#pragma unroll
      for (int j = 0; j < 8; ++j) Vs[(d0 + j) * 64 + key] = vv[j];
    }
    __syncthreads();

    // scores: S[q,key] = Q . K^T
    f32x4 s[2][4];
#pragma unroll
    for (int mi = 0; mi < 2; ++mi)
#pragma unroll
      for (int ni = 0; ni < 4; ++ni) {
        f32x4 a = {};
#pragma unroll
        for (int ks = 0; ks < 2; ++ks) {
          bf16x8 kf = *(const bf16x8*)&Ks[(ni * 16 + l15) * 64 + ks * 32 + l4 * 8];
          a = __builtin_amdgcn_mfma_f32_16x16x32_bf16(qf[mi][ks], kf, a, 0, 0, 0);
        }
        s[mi][ni] = a;
      }

    // online softmax (per query row; rows live in (l>>4)*4+r across 16 lanes)
#pragma unroll
    for (int mi = 0; mi < 2; ++mi) {
      float corr[4], ts[4];
#pragma unroll
      for (int ni = 0; ni < 4; ++ni) s[mi][ni] *= 0.125f;
#pragma unroll
      for (int r = 0; r < 4; ++r) {
        float t = fmaxf(fmaxf(s[mi][0][r], s[mi][1][r]),
                        fmaxf(s[mi][2][r], s[mi][3][r]));
#pragma unroll
        for (int m = 1; m < 16; m <<= 1) t = fmaxf(t, __shfl_xor(t, m, 64));
        float mn = fmaxf(m_s[mi][r], t);
        corr[r] = __expf(m_s[mi][r] - mn);
        m_s[mi][r] = mn;
        ts[r] = 0.f;
      }
#pragma unroll
      for (int ni = 0; ni < 4; ++ni)
#pragma unroll
        for (int r = 0; r < 4; ++r) {
          float p = __expf(s[mi][ni][r] - m_s[mi][r]);
          ts[r] += p;
          Ps[wid][(mi * 16 + l4 * 4 + r) * 64 + ni * 16 + l15] = f2bf(p);
        }
#pragma unroll
      for (int r = 0; r < 4; ++r) {
        float t = ts[r];
#pragma unroll
        for (int m = 1; m < 16; m <<= 1) t += __shfl_xor(t, m, 64);
        l_s[mi][r] = l_s[mi][r] * corr[r] + t;
      }
#pragma unroll
      for (int di = 0; di < 4; ++di)
#pragma unroll
        for (int r = 0; r < 4; ++r) o_acc[mi][di][r] *= corr[r];
    }

    // PV: O += P @ V
    bf16x8 vb[4][2];
#pragma unroll
    for (int di = 0; di < 4; ++di)
#pragma unroll
      for (int ks = 0; ks < 2; ++ks)
        vb[di][ks] = *(const bf16x8*)&Vs[(di * 16 + l15) * 64 + ks * 32 + l4 * 8];
#pragma unroll
    for (int mi = 0; mi < 2; ++mi) {
      bf16x8 pa[2];
#pragma unroll
      for (int ks = 0; ks < 2; ++ks)
        pa[ks] = *(const bf16x8*)&Ps[wid][(mi * 16 + l15) * 64 + ks * 32 + l4 * 8];
#pragma unroll
      for (int di = 0; di < 4; ++di)
#pragma unroll
        for (int ks = 0; ks < 2; ++ks)
          o_acc[mi][di] = __builtin_amdgcn_mfma_f32_16x16x32_bf16(
              pa[ks], vb[di][ks], o_acc[mi][di], 0, 0, 0);
    }
  }

  // epilogue: divide by softmax denom, store bf16
#pragma unroll
  for (int mi = 0; mi < 2; ++mi)
#pragma unroll
    for (int di = 0; di < 4; ++di)
#pragma unroll
      for (int r = 0; r < 4; ++r) {
        int qrow = q0 + wid * 32 + mi * 16 + l4 * 4 + r;
        int dh = di * 16 + l15;
        float val = o_acc[mi][di][r] / l_s[mi][r];
        O[(size_t)qrow * 2048 + h * 64 + dh] = f2bf(val);
      }
}

// ---------- launch ----------
extern "C" void kernel_launch(void* const* d_in, const int* in_sizes, int n_in,
                              void* d_out, int out_size, void* d_ws, size_t ws_size,
                              hipStream_t stream) {
  const float* x  = (const float*)d_in[0];
  const float* Wq = (const float*)d_in[1];
  const float* bq = (const float*)d_in[2];
  const float* Wk = (const float*)d_in[3];
  const float* bk = (const float*)d_in[4];
  const float* Wv = (const float*)d_in[5];
  const float* bv = (const float*)d_in[6];
  const float* qn = (const float*)d_in[7];
  const float* kn = (const float*)d_in[8];
  const float* Wo = (const float*)d_in[9];
  const float* bo = (const float*)d_in[10];

  char* w = (char*)d_ws;
  unsigned short* Xbf = (unsigned short*)(w);                 // 16.78 MB (reused for O)
  unsigned short* Wqb = (unsigned short*)(w + 16777216);      // 8.39 MB
  unsigned short* Wkb = (unsigned short*)(w + 25165824);
  unsigned short* Wvb = (unsigned short*)(w + 33554432);
  unsigned short* Wob = (unsigned short*)(w + 41943040);
  unsigned short* Qb  = (unsigned short*)(w + 50331648);      // 16.78 MB
  unsigned short* Kb  = (unsigned short*)(w + 67108864);
  unsigned short* Vb  = (unsigned short*)(w + 83886080);
  unsigned short* Ob  = Xbf;  // x no longer needed once Q/K/V are built

  const int M = 4096, N = 2048, Kd = 2048;

  // casts
  cast_bf16_kernel<<<1024, 256, 0, stream>>>(x,  Xbf, 8388608 / 4);
  cast_bf16_kernel<<<512, 256, 0, stream>>>(Wq, Wqb, 4194304 / 4);
  cast_bf16_kernel<<<512, 256, 0, stream>>>(Wk, Wkb, 4194304 / 4);
  cast_bf16_kernel<<<512, 256, 0, stream>>>(Wv, Wvb, 4194304 / 4);
  cast_bf16_kernel<<<512, 256, 0, stream>>>(Wo, Wob, 4194304 / 4);

  dim3 gg(N / 128, M / 128);
  gemm_bt<0><<<gg, 256, 0, stream>>>(Xbf, Wqb, bq, Qb, M, N, Kd);
  gemm_bt<0><<<gg, 256, 0, stream>>>(Xbf, Wkb, bk, Kb, M, N, Kd);
  gemm_bt<0><<<gg, 256, 0, stream>>>(Xbf, Wvb, bv, Vb, M, N, Kd);

  rmsnorm_kernel<<<4096, 256, 0, stream>>>(Qb, qn);
  rmsnorm_kernel<<<4096, 256, 0, stream>>>(Kb, kn);

  flash_attn<<<dim3(32, 32), 256, 0, stream>>>(Qb, Kb, Vb, Ob);

  gemm_bt<1><<<gg, 256, 0, stream>>>(Ob, Wob, bo, (float*)d_out, M, N, Kd);
}

// Round 2
// 708.914 us; speedup vs baseline: 1.2146x; 1.2146x over previous
//
#include <hip/hip_runtime.h>

// ---------- types ----------
typedef __bf16 bf16x8 __attribute__((ext_vector_type(8)));
typedef float f32x4 __attribute__((ext_vector_type(4)));
typedef unsigned short u16x8 __attribute__((ext_vector_type(8)));

__device__ __forceinline__ unsigned short f2bf(float f) {
  union { float f; unsigned u; } v; v.f = f;
  unsigned r = (v.u + 0x7fffu + ((v.u >> 16) & 1u)) >> 16;
  return (unsigned short)r;
}
__device__ __forceinline__ float bf2f(unsigned short s) {
  union { unsigned u; float f; } v; v.u = ((unsigned)s) << 16;
  return v.f;
}

#define GLD16(g, l)                                                        \
  __builtin_amdgcn_global_load_lds(                                        \
      (const __attribute__((address_space(1))) void*)(g),                  \
      (__attribute__((address_space(3))) void*)(l), 16, 0, 0)

// XOR swizzle for 64-element (128B) rows: spreads 16B slots across banks.
// sel depends on row bits 0-2 XOR bits 3-5 so both "16 consecutive rows"
// reads and "stride-8 rows" writes are conflict-free.
__device__ __forceinline__ int swzc(int row, int colel) {
  return colel ^ ((((row & 7) ^ ((row >> 3) & 7)) & 7) << 3);
}

// ---------- f32 -> bf16 cast ----------
__global__ __launch_bounds__(256) void cast_bf16_kernel(
    const float* __restrict__ in, unsigned short* __restrict__ out, int n4) {
  int i = blockIdx.x * 256 + threadIdx.x;
  int stride = gridDim.x * 256;
  for (; i < n4; i += stride) {
    float4 f = reinterpret_cast<const float4*>(in)[i];
    ushort4 s;
    s.x = f2bf(f.x); s.y = f2bf(f.y); s.z = f2bf(f.z); s.w = f2bf(f.w);
    reinterpret_cast<ushort4*>(out)[i] = s;
  }
}

// ---------- bf16 NT GEMM: C[m,n] = sum_k A[m,k]*B[n,k] + bias[n] ----------
template <int F32OUT>
__global__ __launch_bounds__(256) void gemm_bt(
    const unsigned short* __restrict__ A, const unsigned short* __restrict__ B,
    const float* __restrict__ bias, void* __restrict__ Cp, int M, int N, int K) {
  __shared__ unsigned short As[128 * 64];
  __shared__ unsigned short Bs[128 * 64];
  const int tid = threadIdx.x;
  const int lane = tid & 63;
  const int wid = tid >> 6;
  const int wr = wid >> 1, wc = wid & 1;
  const int l15 = lane & 15, l4 = lane >> 4;
  const int row0 = blockIdx.y * 128, col0 = blockIdx.x * 128;

  f32x4 acc[4][4] = {};

  const int srow = lane >> 3;
  const int scol = (lane & 7) * 8;

  for (int kt = 0; kt < K; kt += 64) {
    __syncthreads();
#pragma unroll
    for (int i = 0; i < 4; ++i) {
      int c = wid * 4 + i;
      GLD16(A + (size_t)(row0 + c * 8 + srow) * K + kt + scol, &As[c * 512]);
      GLD16(B + (size_t)(col0 + c * 8 + srow) * K + kt + scol, &Bs[c * 512]);
    }
    __syncthreads();
#pragma unroll
    for (int ks = 0; ks < 2; ++ks) {
      const int ko = ks * 32 + l4 * 8;
      bf16x8 af[4], bfr[4];
#pragma unroll
      for (int mi = 0; mi < 4; ++mi)
        af[mi] = *(const bf16x8*)&As[(wr * 64 + mi * 16 + l15) * 64 + ko];
#pragma unroll
      for (int ni = 0; ni < 4; ++ni)
        bfr[ni] = *(const bf16x8*)&Bs[(wc * 64 + ni * 16 + l15) * 64 + ko];
#pragma unroll
      for (int mi = 0; mi < 4; ++mi)
#pragma unroll
        for (int ni = 0; ni < 4; ++ni)
          acc[mi][ni] = __builtin_amdgcn_mfma_f32_16x16x32_bf16(
              af[mi], bfr[ni], acc[mi][ni], 0, 0, 0);
    }
  }

#pragma unroll
  for (int mi = 0; mi < 4; ++mi)
#pragma unroll
    for (int ni = 0; ni < 4; ++ni)
#pragma unroll
      for (int r = 0; r < 4; ++r) {
        int row = row0 + wr * 64 + mi * 16 + l4 * 4 + r;
        int col = col0 + wc * 64 + ni * 16 + l15;
        float v = acc[mi][ni][r] + bias[col];
        if (F32OUT)
          ((float*)Cp)[(size_t)row * N + col] = v;
        else
          ((unsigned short*)Cp)[(size_t)row * N + col] = f2bf(v);
      }
}

// ---------- in-place RMS norm over rows of 2048 (bf16) ----------
__global__ __launch_bounds__(256) void rmsnorm_kernel(
    unsigned short* __restrict__ T, const float* __restrict__ w) {
  const int row = blockIdx.x;
  const int tid = threadIdx.x;
  unsigned short* p = T + (size_t)row * 2048;
  u16x8 v = *(const u16x8*)&p[tid * 8];
  float f[8];
  float ss = 0.f;
#pragma unroll
  for (int j = 0; j < 8; ++j) { f[j] = bf2f(v[j]); ss += f[j] * f[j]; }
#pragma unroll
  for (int m = 1; m < 64; m <<= 1) ss += __shfl_xor(ss, m, 64);
  __shared__ float red[4];
  const int wid = tid >> 6, lane = tid & 63;
  if (lane == 0) red[wid] = ss;
  __syncthreads();
  float tot = red[0] + red[1] + red[2] + red[3];
  float rs = rsqrtf(tot * (1.0f / 2048.0f) + 1e-6f);
  u16x8 o;
#pragma unroll
  for (int j = 0; j < 8; ++j) o[j] = f2bf(f[j] * rs * w[tid * 8 + j]);
  *(u16x8*)&p[tid * 8] = o;
}

// ---------- flash attention: 4096 q x 4096 k, H=32 heads, DH=64 ----------
// grid (32 qtiles, 32 heads), 256 threads. QBLK=128 (32 q/wave), KBLK=64.
// All LDS tiles XOR-swizzled (swzc) to kill bank conflicts on b128 frag reads.
__global__ __launch_bounds__(256) void flash_attn(
    const unsigned short* __restrict__ Q, const unsigned short* __restrict__ K,
    const unsigned short* __restrict__ V, unsigned short* __restrict__ O) {
  __shared__ unsigned short Ks[64 * 64];      // [key][dh], swizzled
  __shared__ unsigned short Vs[64 * 64];      // transposed [dh][key], swizzled
  __shared__ unsigned short Ps[4][32 * 64];   // per-wave P staging, swizzled
  const int h = blockIdx.y;
  const int q0 = blockIdx.x * 128;
  const int tid = threadIdx.x, lane = tid & 63, wid = tid >> 6;
  const int l15 = lane & 15, l4 = lane >> 4;

  // Q fragments (pre-scaled by 1/sqrt(DH)=0.125 — exact in bf16)
  bf16x8 qf[2][2];
#pragma unroll
  for (int mi = 0; mi < 2; ++mi)
#pragma unroll
    for (int ks = 0; ks < 2; ++ks) {
      int qrow = q0 + wid * 32 + mi * 16 + l15;
      bf16x8 raw = *(const bf16x8*)&Q[(size_t)qrow * 2048 + h * 64 + ks * 32 + l4 * 8];
#pragma unroll
      for (int j = 0; j < 8; ++j) qf[mi][ks][j] = (__bf16)((float)raw[j] * 0.125f);
    }

  float m_s[2][4], l_s[2][4];
  f32x4 o_acc[2][4] = {};
#pragma unroll
  for (int mi = 0; mi < 2; ++mi)
#pragma unroll
    for (int r = 0; r < 4; ++r) { m_s[mi][r] = -1e30f; l_s[mi][r] = 0.f; }

  for (int kt = 0; kt < 4096; kt += 64) {
    __syncthreads();
    // stage K tile via async global->LDS; LDS dest linear, swizzle applied
    // to the per-lane GLOBAL source column (inverse == same XOR).
#pragma unroll
    for (int i = 0; i < 2; ++i) {
      int c = wid * 2 + i;                       // chunk: rows c*8 .. c*8+7
      int srow = c * 8 + (lane >> 3);            // row this lane's 16B lands in
      int scol = ((lane & 7) * 8) ^ ((((lane >> 3) ^ c) & 7) << 3);
      GLD16(K + (size_t)(kt + srow) * 2048 + h * 64 + scol, &Ks[c * 512]);
    }
    // stage V transposed via registers, swizzled writes
#pragma unroll
    for (int i = 0; i < 2; ++i) {
      int c2 = i * 256 + tid;
      int key = c2 >> 3, d0 = (c2 & 7) * 8;
      u16x8 vv = *(const u16x8*)&V[(size_t)(kt + key) * 2048 + h * 64 + d0];
#pragma unroll
      for (int j = 0; j < 8; ++j) {
        int row = d0 + j;
        Vs[row * 64 + swzc(row, key)] = vv[j];
      }
    }
    __syncthreads();

    // scores: S[q,key] = Q . K^T   (scale pre-folded into Q)
    f32x4 s[2][4];
#pragma unroll
    for (int mi = 0; mi < 2; ++mi)
#pragma unroll
      for (int ni = 0; ni < 4; ++ni) {
        f32x4 a = {};
#pragma unroll
        for (int ks = 0; ks < 2; ++ks) {
          int krow = ni * 16 + l15;
          bf16x8 kf = *(const bf16x8*)&Ks[krow * 64 + swzc(krow, ks * 32 + l4 * 8)];
          a = __builtin_amdgcn_mfma_f32_16x16x32_bf16(qf[mi][ks], kf, a, 0, 0, 0);
        }
        s[mi][ni] = a;
      }

    // online softmax (rows live in (l>>4)*4+r across 16 lanes)
#pragma unroll
    for (int mi = 0; mi < 2; ++mi) {
      float corr[4], ts[4];
#pragma unroll
      for (int r = 0; r < 4; ++r) {
        float t = fmaxf(fmaxf(s[mi][0][r], s[mi][1][r]),
                        fmaxf(s[mi][2][r], s[mi][3][r]));
#pragma unroll
        for (int m = 1; m < 16; m <<= 1) t = fmaxf(t, __shfl_xor(t, m, 64));
        float mn = fmaxf(m_s[mi][r], t);
        corr[r] = __expf(m_s[mi][r] - mn);
        m_s[mi][r] = mn;
        ts[r] = 0.f;
      }
#pragma unroll
      for (int ni = 0; ni < 4; ++ni)
#pragma unroll
        for (int r = 0; r < 4; ++r) {
          float p = __expf(s[mi][ni][r] - m_s[mi][r]);
          ts[r] += p;
          int prow = mi * 16 + l4 * 4 + r;
          Ps[wid][prow * 64 + swzc(prow, ni * 16 + l15)] = f2bf(p);
        }
#pragma unroll
      for (int r = 0; r < 4; ++r) {
        float t = ts[r];
#pragma unroll
        for (int m = 1; m < 16; m <<= 1) t += __shfl_xor(t, m, 64);
        l_s[mi][r] = l_s[mi][r] * corr[r] + t;
      }
#pragma unroll
      for (int di = 0; di < 4; ++di)
#pragma unroll
        for (int r = 0; r < 4; ++r) o_acc[mi][di][r] *= corr[r];
    }

    // PV: O += P @ V
    bf16x8 vb[4][2];
#pragma unroll
    for (int di = 0; di < 4; ++di)
#pragma unroll
      for (int ks = 0; ks < 2; ++ks) {
        int vrow = di * 16 + l15;
        vb[di][ks] = *(const bf16x8*)&Vs[vrow * 64 + swzc(vrow, ks * 32 + l4 * 8)];
      }
#pragma unroll
    for (int mi = 0; mi < 2; ++mi) {
      bf16x8 pa[2];
#pragma unroll
      for (int ks = 0; ks < 2; ++ks) {
        int prow = mi * 16 + l15;
        pa[ks] = *(const bf16x8*)&Ps[wid][prow * 64 + swzc(prow, ks * 32 + l4 * 8)];
      }
#pragma unroll
      for (int di = 0; di < 4; ++di)
#pragma unroll
        for (int ks = 0; ks < 2; ++ks)
          o_acc[mi][di] = __builtin_amdgcn_mfma_f32_16x16x32_bf16(
              pa[ks], vb[di][ks], o_acc[mi][di], 0, 0, 0);
    }
  }

  // epilogue
#pragma unroll
  for (int mi = 0; mi < 2; ++mi)
#pragma unroll
    for (int di = 0; di < 4; ++di)
#pragma unroll
      for (int r = 0; r < 4; ++r) {
        int qrow = q0 + wid * 32 + mi * 16 + l4 * 4 + r;
        int dh = di * 16 + l15;
        float val = o_acc[mi][di][r] / l_s[mi][r];
        O[(size_t)qrow * 2048 + h * 64 + dh] = f2bf(val);
      }
}

// ---------- launch ----------
extern "C" void kernel_launch(void* const* d_in, const int* in_sizes, int n_in,
                              void* d_out, int out_size, void* d_ws, size_t ws_size,
                              hipStream_t stream) {
  const float* x  = (const float*)d_in[0];
  const float* Wq = (const float*)d_in[1];
  const float* bq = (const float*)d_in[2];
  const float* Wk = (const float*)d_in[3];
  const float* bk = (const float*)d_in[4];
  const float* Wv = (const float*)d_in[5];
  const float* bv = (const float*)d_in[6];
  const float* qn = (const float*)d_in[7];
  const float* kn = (const float*)d_in[8];
  const float* Wo = (const float*)d_in[9];
  const float* bo = (const float*)d_in[10];

  char* w = (char*)d_ws;
  unsigned short* Xbf = (unsigned short*)(w);                 // reused for O
  unsigned short* Wqb = (unsigned short*)(w + 16777216);
  unsigned short* Wkb = (unsigned short*)(w + 25165824);
  unsigned short* Wvb = (unsigned short*)(w + 33554432);
  unsigned short* Wob = (unsigned short*)(w + 41943040);
  unsigned short* Qb  = (unsigned short*)(w + 50331648);
  unsigned short* Kb  = (unsigned short*)(w + 67108864);
  unsigned short* Vb  = (unsigned short*)(w + 83886080);
  unsigned short* Ob  = Xbf;

  const int M = 4096, N = 2048, Kd = 2048;

  cast_bf16_kernel<<<1024, 256, 0, stream>>>(x,  Xbf, 8388608 / 4);
  cast_bf16_kernel<<<512, 256, 0, stream>>>(Wq, Wqb, 4194304 / 4);
  cast_bf16_kernel<<<512, 256, 0, stream>>>(Wk, Wkb, 4194304 / 4);
  cast_bf16_kernel<<<512, 256, 0, stream>>>(Wv, Wvb, 4194304 / 4);
  cast_bf16_kernel<<<512, 256, 0, stream>>>(Wo, Wob, 4194304 / 4);

  dim3 gg(N / 128, M / 128);
  gemm_bt<0><<<gg, 256, 0, stream>>>(Xbf, Wqb, bq, Qb, M, N, Kd);
  gemm_bt<0><<<gg, 256, 0, stream>>>(Xbf, Wkb, bk, Kb, M, N, Kd);
  gemm_bt<0><<<gg, 256, 0, stream>>>(Xbf, Wvb, bv, Vb, M, N, Kd);

  rmsnorm_kernel<<<4096, 256, 0, stream>>>(Qb, qn);
  rmsnorm_kernel<<<4096, 256, 0, stream>>>(Kb, kn);

  flash_attn<<<dim3(32, 32), 256, 0, stream>>>(Qb, Kb, Vb, Ob);

  gemm_bt<1><<<gg, 256, 0, stream>>>(Ob, Wob, bo, (float*)d_out, M, N, Kd);
}

// Round 3
// 476.502 us; speedup vs baseline: 1.8070x; 1.4877x over previous
//
#include <hip/hip_runtime.h>

// ---------- types ----------
typedef __bf16 bf16x8 __attribute__((ext_vector_type(8)));
typedef float f32x4 __attribute__((ext_vector_type(4)));
typedef float f32x16 __attribute__((ext_vector_type(16)));
typedef unsigned short u16x8 __attribute__((ext_vector_type(8)));
typedef unsigned u32x2 __attribute__((ext_vector_type(2)));
typedef unsigned u32x4 __attribute__((ext_vector_type(4)));

__device__ __forceinline__ unsigned short f2bf(float f) {
  union { float f; unsigned u; } v; v.f = f;
  unsigned r = (v.u + 0x7fffu + ((v.u >> 16) & 1u)) >> 16;
  return (unsigned short)r;
}
__device__ __forceinline__ float bf2f(unsigned short s) {
  union { unsigned u; float f; } v; v.u = ((unsigned)s) << 16;
  return v.f;
}

#define GLD16(g, l)                                                        \
  __builtin_amdgcn_global_load_lds(                                        \
      (const __attribute__((address_space(1))) void*)(g),                  \
      (__attribute__((address_space(3))) void*)(l), 16, 0, 0)

// XOR swizzle for 64-element (128B) rows.
__device__ __forceinline__ int swzc(int row, int colel) {
  return colel ^ ((((row & 7) ^ ((row >> 3) & 7)) & 7) << 3);
}

// permlane32_swap: exchanges upper half of a with lower half of b.
// returns {a', b'}: a'[l>=32] = b[l-32]; b'[l<32] = a[l+32].
__device__ __forceinline__ u32x2 plswap(unsigned a, unsigned b) {
  return __builtin_amdgcn_permlane32_swap(a, b, false, false);
}
__device__ __forceinline__ float pair_max(float x) {
  u32x2 r = plswap(__float_as_uint(x), __float_as_uint(x));
  return fmaxf(__uint_as_float(r.x), __uint_as_float(r.y));
}
__device__ __forceinline__ float pair_sum(float x) {
  u32x2 r = plswap(__float_as_uint(x), __float_as_uint(x));
  return __uint_as_float(r.x) + __uint_as_float(r.y);
}
__device__ __forceinline__ unsigned cvtpk(float a, float b) {
  unsigned r;
  asm("v_cvt_pk_bf16_f32 %0, %1, %2" : "=v"(r) : "v"(a), "v"(b));
  return r;
}

// ---------- f32 -> bf16 cast ----------
__global__ __launch_bounds__(256) void cast_bf16_kernel(
    const float* __restrict__ in, unsigned short* __restrict__ out, int n4) {
  int i = blockIdx.x * 256 + threadIdx.x;
  int stride = gridDim.x * 256;
  for (; i < n4; i += stride) {
    float4 f = reinterpret_cast<const float4*>(in)[i];
    ushort4 s;
    s.x = f2bf(f.x); s.y = f2bf(f.y); s.z = f2bf(f.z); s.w = f2bf(f.w);
    reinterpret_cast<ushort4*>(out)[i] = s;
  }
}

// ---------- bf16 NT GEMM (unchanged from round 2) ----------
template <int F32OUT>
__global__ __launch_bounds__(256) void gemm_bt(
    const unsigned short* __restrict__ A, const unsigned short* __restrict__ B,
    const float* __restrict__ bias, void* __restrict__ Cp, int M, int N, int K) {
  __shared__ unsigned short As[128 * 64];
  __shared__ unsigned short Bs[128 * 64];
  const int tid = threadIdx.x;
  const int lane = tid & 63;
  const int wid = tid >> 6;
  const int wr = wid >> 1, wc = wid & 1;
  const int l15 = lane & 15, l4 = lane >> 4;
  const int row0 = blockIdx.y * 128, col0 = blockIdx.x * 128;

  f32x4 acc[4][4] = {};

  const int srow = lane >> 3;
  const int scol = (lane & 7) * 8;

  for (int kt = 0; kt < K; kt += 64) {
    __syncthreads();
#pragma unroll
    for (int i = 0; i < 4; ++i) {
      int c = wid * 4 + i;
      GLD16(A + (size_t)(row0 + c * 8 + srow) * K + kt + scol, &As[c * 512]);
      GLD16(B + (size_t)(col0 + c * 8 + srow) * K + kt + scol, &Bs[c * 512]);
    }
    __syncthreads();
#pragma unroll
    for (int ks = 0; ks < 2; ++ks) {
      const int ko = ks * 32 + l4 * 8;
      bf16x8 af[4], bfr[4];
#pragma unroll
      for (int mi = 0; mi < 4; ++mi)
        af[mi] = *(const bf16x8*)&As[(wr * 64 + mi * 16 + l15) * 64 + ko];
#pragma unroll
      for (int ni = 0; ni < 4; ++ni)
        bfr[ni] = *(const bf16x8*)&Bs[(wc * 64 + ni * 16 + l15) * 64 + ko];
#pragma unroll
      for (int mi = 0; mi < 4; ++mi)
#pragma unroll
        for (int ni = 0; ni < 4; ++ni)
          acc[mi][ni] = __builtin_amdgcn_mfma_f32_16x16x32_bf16(
              af[mi], bfr[ni], acc[mi][ni], 0, 0, 0);
    }
  }

#pragma unroll
  for (int mi = 0; mi < 4; ++mi)
#pragma unroll
    for (int ni = 0; ni < 4; ++ni)
#pragma unroll
      for (int r = 0; r < 4; ++r) {
        int row = row0 + wr * 64 + mi * 16 + l4 * 4 + r;
        int col = col0 + wc * 64 + ni * 16 + l15;
        float v = acc[mi][ni][r] + bias[col];
        if (F32OUT)
          ((float*)Cp)[(size_t)row * N + col] = v;
        else
          ((unsigned short*)Cp)[(size_t)row * N + col] = f2bf(v);
      }
}

// ---------- in-place RMS norm over rows of 2048 (bf16) ----------
__global__ __launch_bounds__(256) void rmsnorm_kernel(
    unsigned short* __restrict__ T, const float* __restrict__ w) {
  const int row = blockIdx.x;
  const int tid = threadIdx.x;
  unsigned short* p = T + (size_t)row * 2048;
  u16x8 v = *(const u16x8*)&p[tid * 8];
  float f[8];
  float ss = 0.f;
#pragma unroll
  for (int j = 0; j < 8; ++j) { f[j] = bf2f(v[j]); ss += f[j] * f[j]; }
#pragma unroll
  for (int m = 1; m < 64; m <<= 1) ss += __shfl_xor(ss, m, 64);
  __shared__ float red[4];
  const int wid = tid >> 6, lane = tid & 63;
  if (lane == 0) red[wid] = ss;
  __syncthreads();
  float tot = red[0] + red[1] + red[2] + red[3];
  float rs = rsqrtf(tot * (1.0f / 2048.0f) + 1e-6f);
  u16x8 o;
#pragma unroll
  for (int j = 0; j < 8; ++j) o[j] = f2bf(f[j] * rs * w[tid * 8 + j]);
  *(u16x8*)&p[tid * 8] = o;
}

// ---------- flash attention, swapped-operand 32x32 structure ----------
// 1024 blocks (XCD-swizzled: 4 heads per XCD), 4 waves/block, 32 q/wave.
// Per tile: S^T = mfma(K,Q) -> lane holds 32 scores of one q (q = lane&31,
// keys split across hi = lane>>5). In-register softmax (log2 domain),
// cvt_pk + permlane32_swap builds PV B-frags in-register. O^T = mfma(V^T,P^T).
__global__ __launch_bounds__(256) void flash_attn(
    const unsigned short* __restrict__ Q, const unsigned short* __restrict__ K,
    const unsigned short* __restrict__ V, unsigned short* __restrict__ O) {
  __shared__ unsigned short Ks[64 * 64];      // [key][dh], swizzled
  __shared__ unsigned short Vs[64 * 64];      // transposed [dh][key], swizzled
  const int bid = blockIdx.x;
  const int sw = (bid & 7) * 128 + (bid >> 3);   // XCD-chunked (1024 % 8 == 0)
  const int h = sw >> 5;
  const int q0 = (sw & 31) * 128;
  const int tid = threadIdx.x, lane = tid & 63, wid = tid >> 6;
  const int l31 = lane & 31, hi = lane >> 5;

  // Q B-frags: lane holds Q[q0+wid*32+l31][kt16*16 + hi*8 + j], pre-scaled
  // by 0.125*log2(e) so softmax runs in exp2 domain.
  const float QSCALE = 0.125f * 1.44269504f;
  bf16x8 qf[4];
  {
    const int qrow = q0 + wid * 32 + l31;
#pragma unroll
    for (int kt = 0; kt < 4; ++kt) {
      bf16x8 raw = *(const bf16x8*)&Q[(size_t)qrow * 2048 + h * 64 + kt * 16 + hi * 8];
#pragma unroll
      for (int j = 0; j < 8; ++j) qf[kt][j] = (__bf16)((float)raw[j] * QSCALE);
    }
  }

  float m_r = -1e30f, l_r = 0.f;
  f32x16 oa[2] = {};

  for (int kt0 = 0; kt0 < 4096; kt0 += 64) {
    __syncthreads();
    // ---- stage K [key][dh] via global_load_lds, source pre-swizzled ----
#pragma unroll
    for (int i = 0; i < 2; ++i) {
      int c = wid * 2 + i;
      int srow = c * 8 + (lane >> 3);
      int scol = ((lane & 7) * 8) ^ ((((lane >> 3) ^ c) & 7) << 3);
      GLD16(K + (size_t)(kt0 + srow) * 2048 + h * 64 + scol, &Ks[c * 512]);
    }
    // ---- stage V transposed [dh][key], paired-key u32 writes ----
    {
      int a = tid & 31, d0 = (tid >> 5) * 8;
      u16x8 va = *(const u16x8*)&V[(size_t)(kt0 + 2 * a) * 2048 + h * 64 + d0];
      u16x8 vb = *(const u16x8*)&V[(size_t)(kt0 + 2 * a + 1) * 2048 + h * 64 + d0];
#pragma unroll
      for (int j = 0; j < 8; ++j) {
        int row = d0 + j;
        int col2 = swzc(row, 2 * a);
        *(unsigned*)&Vs[row * 64 + col2] = (unsigned)va[j] | ((unsigned)vb[j] << 16);
      }
    }
    __syncthreads();

    // ---- S^T[kb]: keys kb*32+(reg-mapped), cols q = l31 ----
    f32x16 st[2];
#pragma unroll
    for (int kb = 0; kb < 2; ++kb) {
      f32x16 a = {};
      const int row = kb * 32 + l31;
#pragma unroll
      for (int kt = 0; kt < 4; ++kt) {
        bf16x8 kf = *(const bf16x8*)&Ks[row * 64 + swzc(row, kt * 16 + hi * 8)];
        a = __builtin_amdgcn_mfma_f32_32x32x16_bf16(kf, qf[kt], a, 0, 0, 0);
      }
      st[kb] = a;
    }

    // ---- in-lane max tree + cross-hi combine ----
    float t[16];
#pragma unroll
    for (int j = 0; j < 16; ++j) t[j] = fmaxf(st[0][j], st[1][j]);
#pragma unroll
    for (int sdist = 8; sdist >= 1; sdist >>= 1)
#pragma unroll
      for (int j = 0; j < 8; ++j)
        if (j < sdist) t[j] = fmaxf(t[j], t[j + sdist]);
    float tmax = pair_max(t[0]);

    // ---- defer-max rescale (T13) ----
    if (!__all(tmax <= m_r + 11.0f)) {
      float mn = fmaxf(m_r, tmax);
      float corr = __builtin_amdgcn_exp2f(m_r - mn);
      l_r *= corr;
#pragma unroll
      for (int dv = 0; dv < 2; ++dv)
#pragma unroll
        for (int r = 0; r < 16; ++r) oa[dv][r] *= corr;
      m_r = mn;
    }

    // ---- P = exp2(S - m), pack to bf16 pairs, sum ----
    unsigned pk[16];
    float s0 = 0.f, s1 = 0.f, s2 = 0.f, s3 = 0.f;
#pragma unroll
    for (int kb = 0; kb < 2; ++kb)
#pragma unroll
      for (int j = 0; j < 8; ++j) {
        float pa = __builtin_amdgcn_exp2f(st[kb][2 * j] - m_r);
        float pb = __builtin_amdgcn_exp2f(st[kb][2 * j + 1] - m_r);
        if ((j & 3) == 0) s0 += pa + pb;
        else if ((j & 3) == 1) s1 += pa + pb;
        else if ((j & 3) == 2) s2 += pa + pb;
        else s3 += pa + pb;
        pk[kb * 8 + j] = cvtpk(pa, pb);
      }
    l_r += pair_sum(((s0 + s1) + (s2 + s3)));

    // ---- build PV B-frags in-register via permlane32_swap ----
    // pk bases (k w/o hi): {0,2,8,10,16,18,24,26}+32*kb. frag[kt] words:
    // {swap(pk[4kt],pk[4kt+2]).x, swap(pk[4kt+1],pk[4kt+3]).x,
    //  swap(pk[4kt],pk[4kt+2]).y, swap(pk[4kt+1],pk[4kt+3]).y}
    bf16x8 pfrag[4];
#pragma unroll
    for (int kt = 0; kt < 4; ++kt) {
      u32x2 sa = plswap(pk[4 * kt + 0], pk[4 * kt + 2]);
      u32x2 sb = plswap(pk[4 * kt + 1], pk[4 * kt + 3]);
      union { u32x4 u; bf16x8 b; } w;
      w.u.x = sa.x; w.u.y = sb.x; w.u.z = sa.y; w.u.w = sb.y;
      pfrag[kt] = w.b;
    }

    // ---- PV: O^T[dv] += V^T-frag @ P^T-frag ----
#pragma unroll
    for (int dv = 0; dv < 2; ++dv) {
      const int row = dv * 32 + l31;
#pragma unroll
      for (int kt = 0; kt < 4; ++kt) {
        bf16x8 vf = *(const bf16x8*)&Vs[row * 64 + swzc(row, kt * 16 + hi * 8)];
        oa[dv] = __builtin_amdgcn_mfma_f32_32x32x16_bf16(vf, pfrag[kt], oa[dv], 0, 0, 0);
      }
    }
  }

  // ---- epilogue: O[q][dh] = oa^T / l ----
  const float inv = 1.0f / l_r;
  const int qrow = q0 + wid * 32 + l31;
#pragma unroll
  for (int dv = 0; dv < 2; ++dv)
#pragma unroll
    for (int r = 0; r < 16; ++r) {
      int dh = (r & 3) + 8 * (r >> 2) + 4 * hi + 32 * dv;
      O[(size_t)qrow * 2048 + h * 64 + dh] = f2bf(oa[dv][r] * inv);
    }
}

// ---------- launch ----------
extern "C" void kernel_launch(void* const* d_in, const int* in_sizes, int n_in,
                              void* d_out, int out_size, void* d_ws, size_t ws_size,
                              hipStream_t stream) {
  const float* x  = (const float*)d_in[0];
  const float* Wq = (const float*)d_in[1];
  const float* bq = (const float*)d_in[2];
  const float* Wk = (const float*)d_in[3];
  const float* bk = (const float*)d_in[4];
  const float* Wv = (const float*)d_in[5];
  const float* bv = (const float*)d_in[6];
  const float* qn = (const float*)d_in[7];
  const float* kn = (const float*)d_in[8];
  const float* Wo = (const float*)d_in[9];
  const float* bo = (const float*)d_in[10];

  char* w = (char*)d_ws;
  unsigned short* Xbf = (unsigned short*)(w);                 // reused for O
  unsigned short* Wqb = (unsigned short*)(w + 16777216);
  unsigned short* Wkb = (unsigned short*)(w + 25165824);
  unsigned short* Wvb = (unsigned short*)(w + 33554432);
  unsigned short* Wob = (unsigned short*)(w + 41943040);
  unsigned short* Qb  = (unsigned short*)(w + 50331648);
  unsigned short* Kb  = (unsigned short*)(w + 67108864);
  unsigned short* Vb  = (unsigned short*)(w + 83886080);
  unsigned short* Ob  = Xbf;

  const int M = 4096, N = 2048, Kd = 2048;

  cast_bf16_kernel<<<1024, 256, 0, stream>>>(x,  Xbf, 8388608 / 4);
  cast_bf16_kernel<<<512, 256, 0, stream>>>(Wq, Wqb, 4194304 / 4);
  cast_bf16_kernel<<<512, 256, 0, stream>>>(Wk, Wkb, 4194304 / 4);
  cast_bf16_kernel<<<512, 256, 0, stream>>>(Wv, Wvb, 4194304 / 4);
  cast_bf16_kernel<<<512, 256, 0, stream>>>(Wo, Wob, 4194304 / 4);

  dim3 gg(N / 128, M / 128);
  gemm_bt<0><<<gg, 256, 0, stream>>>(Xbf, Wqb, bq, Qb, M, N, Kd);
  gemm_bt<0><<<gg, 256, 0, stream>>>(Xbf, Wkb, bk, Kb, M, N, Kd);
  gemm_bt<0><<<gg, 256, 0, stream>>>(Xbf, Wvb, bv, Vb, M, N, Kd);

  rmsnorm_kernel<<<4096, 256, 0, stream>>>(Qb, qn);
  rmsnorm_kernel<<<4096, 256, 0, stream>>>(Kb, kn);

  flash_attn<<<1024, 256, 0, stream>>>(Qb, Kb, Vb, Ob);

  gemm_bt<1><<<gg, 256, 0, stream>>>(Ob, Wob, bo, (float*)d_out, M, N, Kd);
}

// Round 4
// 425.440 us; speedup vs baseline: 2.0239x; 1.1200x over previous
//
#include <hip/hip_runtime.h>

// ---------- types ----------
typedef __bf16 bf16x8 __attribute__((ext_vector_type(8)));
typedef float f32x4 __attribute__((ext_vector_type(4)));
typedef float f32x16 __attribute__((ext_vector_type(16)));
typedef unsigned short u16x8 __attribute__((ext_vector_type(8)));
typedef unsigned u32x2 __attribute__((ext_vector_type(2)));
typedef unsigned u32x4 __attribute__((ext_vector_type(4)));

__device__ __forceinline__ unsigned short f2bf(float f) {
  union { float f; unsigned u; } v; v.f = f;
  unsigned r = (v.u + 0x7fffu + ((v.u >> 16) & 1u)) >> 16;
  return (unsigned short)r;
}
__device__ __forceinline__ float bf2f(unsigned short s) {
  union { unsigned u; float f; } v; v.u = ((unsigned)s) << 16;
  return v.f;
}

#define GLD16(g, l)                                                        \
  __builtin_amdgcn_global_load_lds(                                        \
      (const __attribute__((address_space(1))) void*)(g),                  \
      (__attribute__((address_space(3))) void*)(l), 16, 0, 0)

// XOR swizzle for 64-element (128B) rows.
__device__ __forceinline__ int swzc(int row, int colel) {
  return colel ^ ((((row & 7) ^ ((row >> 3) & 7)) & 7) << 3);
}

__device__ __forceinline__ u32x2 plswap(unsigned a, unsigned b) {
  return __builtin_amdgcn_permlane32_swap(a, b, false, false);
}
__device__ __forceinline__ float pair_max(float x) {
  u32x2 r = plswap(__float_as_uint(x), __float_as_uint(x));
  return fmaxf(__uint_as_float(r.x), __uint_as_float(r.y));
}
__device__ __forceinline__ float pair_sum(float x) {
  u32x2 r = plswap(__float_as_uint(x), __float_as_uint(x));
  return __uint_as_float(r.x) + __uint_as_float(r.y);
}
__device__ __forceinline__ unsigned cvtpk(float a, float b) {
  unsigned r;
  asm("v_cvt_pk_bf16_f32 %0, %1, %2" : "=v"(r) : "v"(a), "v"(b));
  return r;
}
__device__ __forceinline__ float F3(float a, float b, float c) {
  return fmaxf(fmaxf(a, b), c);  // fuses to v_max3_f32
}

// ---------- f32 -> bf16 cast ----------
__global__ __launch_bounds__(256) void cast_bf16_kernel(
    const float* __restrict__ in, unsigned short* __restrict__ out, int n4) {
  int i = blockIdx.x * 256 + threadIdx.x;
  int stride = gridDim.x * 256;
  for (; i < n4; i += stride) {
    float4 f = reinterpret_cast<const float4*>(in)[i];
    ushort4 s;
    s.x = f2bf(f.x); s.y = f2bf(f.y); s.z = f2bf(f.z); s.w = f2bf(f.w);
    reinterpret_cast<ushort4*>(out)[i] = s;
  }
}

// ---------- bf16 NT GEMM ----------
template <int F32OUT>
__global__ __launch_bounds__(256) void gemm_bt(
    const unsigned short* __restrict__ A, const unsigned short* __restrict__ B,
    const float* __restrict__ bias, void* __restrict__ Cp, int M, int N, int K) {
  __shared__ unsigned short As[128 * 64];
  __shared__ unsigned short Bs[128 * 64];
  const int tid = threadIdx.x;
  const int lane = tid & 63;
  const int wid = tid >> 6;
  const int wr = wid >> 1, wc = wid & 1;
  const int l15 = lane & 15, l4 = lane >> 4;
  const int row0 = blockIdx.y * 128, col0 = blockIdx.x * 128;

  f32x4 acc[4][4] = {};

  const int srow = lane >> 3;
  const int scol = (lane & 7) * 8;

  for (int kt = 0; kt < K; kt += 64) {
    __syncthreads();
#pragma unroll
    for (int i = 0; i < 4; ++i) {
      int c = wid * 4 + i;
      GLD16(A + (size_t)(row0 + c * 8 + srow) * K + kt + scol, &As[c * 512]);
      GLD16(B + (size_t)(col0 + c * 8 + srow) * K + kt + scol, &Bs[c * 512]);
    }
    __syncthreads();
#pragma unroll
    for (int ks = 0; ks < 2; ++ks) {
      const int ko = ks * 32 + l4 * 8;
      bf16x8 af[4], bfr[4];
#pragma unroll
      for (int mi = 0; mi < 4; ++mi)
        af[mi] = *(const bf16x8*)&As[(wr * 64 + mi * 16 + l15) * 64 + ko];
#pragma unroll
      for (int ni = 0; ni < 4; ++ni)
        bfr[ni] = *(const bf16x8*)&Bs[(wc * 64 + ni * 16 + l15) * 64 + ko];
#pragma unroll
      for (int mi = 0; mi < 4; ++mi)
#pragma unroll
        for (int ni = 0; ni < 4; ++ni)
          acc[mi][ni] = __builtin_amdgcn_mfma_f32_16x16x32_bf16(
              af[mi], bfr[ni], acc[mi][ni], 0, 0, 0);
    }
  }

#pragma unroll
  for (int mi = 0; mi < 4; ++mi)
#pragma unroll
    for (int ni = 0; ni < 4; ++ni)
#pragma unroll
      for (int r = 0; r < 4; ++r) {
        int row = row0 + wr * 64 + mi * 16 + l4 * 4 + r;
        int col = col0 + wc * 64 + ni * 16 + l15;
        float v = acc[mi][ni][r] + bias[col];
        if (F32OUT)
          ((float*)Cp)[(size_t)row * N + col] = v;
        else
          ((unsigned short*)Cp)[(size_t)row * N + col] = f2bf(v);
      }
}

// ---------- in-place RMS norm over rows of 2048 (bf16) ----------
__global__ __launch_bounds__(256) void rmsnorm_kernel(
    unsigned short* __restrict__ T, const float* __restrict__ w) {
  const int row = blockIdx.x;
  const int tid = threadIdx.x;
  unsigned short* p = T + (size_t)row * 2048;
  u16x8 v = *(const u16x8*)&p[tid * 8];
  float f[8];
  float ss = 0.f;
#pragma unroll
  for (int j = 0; j < 8; ++j) { f[j] = bf2f(v[j]); ss += f[j] * f[j]; }
#pragma unroll
  for (int m = 1; m < 64; m <<= 1) ss += __shfl_xor(ss, m, 64);
  __shared__ float red[4];
  const int wid = tid >> 6, lane = tid & 63;
  if (lane == 0) red[wid] = ss;
  __syncthreads();
  float tot = red[0] + red[1] + red[2] + red[3];
  float rs = rsqrtf(tot * (1.0f / 2048.0f) + 1e-6f);
  u16x8 o;
#pragma unroll
  for (int j = 0; j < 8; ++j) o[j] = f2bf(f[j] * rs * w[tid * 8 + j]);
  *(u16x8*)&p[tid * 8] = o;
}

// ---------- flash attention, swapped-operand 32x32, double-buffered ----------
// 1024 blocks (XCD-swizzled), 4 waves/block, 32 q/wave, KVBLK=64.
// Per tile: issue next-tile global loads -> compute current (S^T = mfma(K,Q),
// in-register softmax, O^T = mfma(V^T,P^T)) -> ds_write next buffer -> barrier.
__global__ __launch_bounds__(256, 4) void flash_attn(
    const unsigned short* __restrict__ Q, const unsigned short* __restrict__ K,
    const unsigned short* __restrict__ V, unsigned short* __restrict__ O) {
  __shared__ unsigned short Ks[2][64 * 64];   // [key][dh], swizzled
  __shared__ unsigned short Vs[2][64 * 64];   // transposed [dh][key], swizzled
  const int bid = blockIdx.x;
  const int sw = (bid & 7) * 128 + (bid >> 3);   // XCD-chunked (1024 % 8 == 0)
  const int h = sw >> 5;
  const int q0 = (sw & 31) * 128;
  const int tid = threadIdx.x, lane = tid & 63, wid = tid >> 6;
  const int l31 = lane & 31, hi = lane >> 5;

  // staging geometry (per lane)
  const int kr0 = wid * 16 + (lane >> 3);    // K rows kr0, kr0+8
  const int kc0 = (lane & 7) * 8;
  const int vkey = (tid & 31) * 2;           // V key pair
  const int vd0 = (tid >> 5) * 8;            // V dh group

  // Q B-frags, pre-scaled by 0.125*log2(e) (exp2-domain softmax)
  const float QSCALE = 0.125f * 1.44269504f;
  bf16x8 qf[4];
  {
    const int qrow = q0 + wid * 32 + l31;
#pragma unroll
    for (int kt = 0; kt < 4; ++kt) {
      bf16x8 raw = *(const bf16x8*)&Q[(size_t)qrow * 2048 + h * 64 + kt * 16 + hi * 8];
#pragma unroll
      for (int j = 0; j < 8; ++j) qf[kt][j] = (__bf16)((float)raw[j] * QSCALE);
    }
  }

  float m_r = -1e30f, l_r = 0.f;
  f32x16 oa[2] = {};

  u16x8 kreg0, kreg1, vreg0, vreg1;
  auto loadKV = [&](int kt0) {
    kreg0 = *(const u16x8*)&K[(size_t)(kt0 + kr0) * 2048 + h * 64 + kc0];
    kreg1 = *(const u16x8*)&K[(size_t)(kt0 + kr0 + 8) * 2048 + h * 64 + kc0];
    vreg0 = *(const u16x8*)&V[(size_t)(kt0 + vkey) * 2048 + h * 64 + vd0];
    vreg1 = *(const u16x8*)&V[(size_t)(kt0 + vkey + 1) * 2048 + h * 64 + vd0];
  };
  auto writeKV = [&](int b) {
    *(u16x8*)&Ks[b][kr0 * 64 + swzc(kr0, kc0)] = kreg0;
    *(u16x8*)&Ks[b][(kr0 + 8) * 64 + swzc(kr0 + 8, kc0)] = kreg1;
#pragma unroll
    for (int d = 0; d < 8; ++d) {
      int row = vd0 + d;
      *(unsigned*)&Vs[b][row * 64 + swzc(row, vkey)] =
          (unsigned)vreg0[d] | ((unsigned)vreg1[d] << 16);
    }
  };

  // prologue: stage tile 0 into buffer 0
  loadKV(0);
  writeKV(0);
  __syncthreads();

  for (int t = 0; t < 64; ++t) {
    const int cur = t & 1;
    // issue next-tile global loads early — latency hides under compute
    if (t < 63) loadKV((t + 1) * 64);

    // ---- S^T = mfma(K, Q): lane holds 32 scores of query q = l31 ----
    f32x16 st[2];
    __builtin_amdgcn_s_setprio(1);
#pragma unroll
    for (int kb = 0; kb < 2; ++kb) {
      f32x16 a = {};
      const int row = kb * 32 + l31;
#pragma unroll
      for (int kt = 0; kt < 4; ++kt) {
        bf16x8 kf = *(const bf16x8*)&Ks[cur][row * 64 + swzc(row, kt * 16 + hi * 8)];
        a = __builtin_amdgcn_mfma_f32_32x32x16_bf16(kf, qf[kt], a, 0, 0, 0);
      }
      st[kb] = a;
    }
    __builtin_amdgcn_s_setprio(0);

    // ---- max reduce (max3 triples) ----
    float t8[8];
#pragma unroll
    for (int j = 0; j < 8; ++j)
      t8[j] = fmaxf(F3(st[0][2 * j], st[0][2 * j + 1], st[1][2 * j]),
                    st[1][2 * j + 1]);
    float tmax = pair_max(F3(F3(t8[0], t8[1], t8[2]), F3(t8[3], t8[4], t8[5]),
                             fmaxf(t8[6], t8[7])));

    // ---- defer-max rescale (T13, THR=11 in log2 domain) ----
    if (!__all(tmax <= m_r + 11.0f)) {
      float mn = fmaxf(m_r, tmax);
      float corr = __builtin_amdgcn_exp2f(m_r - mn);
      l_r *= corr;
#pragma unroll
      for (int dv = 0; dv < 2; ++dv)
#pragma unroll
        for (int r = 0; r < 16; ++r) oa[dv][r] *= corr;
      m_r = mn;
    }

    // ---- P = exp2(S - m), pack to bf16 pairs, sum ----
    unsigned pk[16];
    float s0 = 0.f, s1 = 0.f, s2 = 0.f, s3 = 0.f;
#pragma unroll
    for (int kb = 0; kb < 2; ++kb)
#pragma unroll
      for (int j = 0; j < 8; ++j) {
        float pa = __builtin_amdgcn_exp2f(st[kb][2 * j] - m_r);
        float pb = __builtin_amdgcn_exp2f(st[kb][2 * j + 1] - m_r);
        if ((j & 3) == 0) s0 += pa + pb;
        else if ((j & 3) == 1) s1 += pa + pb;
        else if ((j & 3) == 2) s2 += pa + pb;
        else s3 += pa + pb;
        pk[kb * 8 + j] = cvtpk(pa, pb);
      }
    l_r += pair_sum(((s0 + s1) + (s2 + s3)));

    // ---- build PV B-frags in-register via permlane32_swap ----
    bf16x8 pfrag[4];
#pragma unroll
    for (int kt = 0; kt < 4; ++kt) {
      u32x2 sa = plswap(pk[4 * kt + 0], pk[4 * kt + 2]);
      u32x2 sb = plswap(pk[4 * kt + 1], pk[4 * kt + 3]);
      union { u32x4 u; bf16x8 b; } w;
      w.u.x = sa.x; w.u.y = sb.x; w.u.z = sa.y; w.u.w = sb.y;
      pfrag[kt] = w.b;
    }

    // ---- PV: O^T[dv] += V^T-frag @ P^T-frag ----
    __builtin_amdgcn_s_setprio(1);
#pragma unroll
    for (int dv = 0; dv < 2; ++dv) {
      const int row = dv * 32 + l31;
#pragma unroll
      for (int kt = 0; kt < 4; ++kt) {
        bf16x8 vf = *(const bf16x8*)&Vs[cur][row * 64 + swzc(row, kt * 16 + hi * 8)];
        oa[dv] = __builtin_amdgcn_mfma_f32_32x32x16_bf16(vf, pfrag[kt], oa[dv], 0, 0, 0);
      }
    }
    __builtin_amdgcn_s_setprio(0);

    // ---- write next buffer (vmcnt waits land here), single barrier ----
    if (t < 63) {
      writeKV(cur ^ 1);
      __syncthreads();
    }
  }

  // ---- epilogue: vectorized O store (4 consecutive dh per u32x2) ----
  const float inv = 1.0f / l_r;
  const int qrow = q0 + wid * 32 + l31;
#pragma unroll
  for (int dv = 0; dv < 2; ++dv)
#pragma unroll
    for (int tq = 0; tq < 4; ++tq) {
      unsigned w0 = cvtpk(oa[dv][4 * tq + 0] * inv, oa[dv][4 * tq + 1] * inv);
      unsigned w1 = cvtpk(oa[dv][4 * tq + 2] * inv, oa[dv][4 * tq + 3] * inv);
      int dh = 32 * dv + 8 * tq + 4 * hi;
      u32x2 w2 = {w0, w1};
      *(u32x2*)&O[(size_t)qrow * 2048 + h * 64 + dh] = w2;
    }
}

// ---------- launch ----------
extern "C" void kernel_launch(void* const* d_in, const int* in_sizes, int n_in,
                              void* d_out, int out_size, void* d_ws, size_t ws_size,
                              hipStream_t stream) {
  const float* x  = (const float*)d_in[0];
  const float* Wq = (const float*)d_in[1];
  const float* bq = (const float*)d_in[2];
  const float* Wk = (const float*)d_in[3];
  const float* bk = (const float*)d_in[4];
  const float* Wv = (const float*)d_in[5];
  const float* bv = (const float*)d_in[6];
  const float* qn = (const float*)d_in[7];
  const float* kn = (const float*)d_in[8];
  const float* Wo = (const float*)d_in[9];
  const float* bo = (const float*)d_in[10];

  char* w = (char*)d_ws;
  unsigned short* Xbf = (unsigned short*)(w);                 // reused for O
  unsigned short* Wqb = (unsigned short*)(w + 16777216);
  unsigned short* Wkb = (unsigned short*)(w + 25165824);
  unsigned short* Wvb = (unsigned short*)(w + 33554432);
  unsigned short* Wob = (unsigned short*)(w + 41943040);
  unsigned short* Qb  = (unsigned short*)(w + 50331648);
  unsigned short* Kb  = (unsigned short*)(w + 67108864);
  unsigned short* Vb  = (unsigned short*)(w + 83886080);
  unsigned short* Ob  = Xbf;

  const int M = 4096, N = 2048, Kd = 2048;

  cast_bf16_kernel<<<1024, 256, 0, stream>>>(x,  Xbf, 8388608 / 4);
  cast_bf16_kernel<<<512, 256, 0, stream>>>(Wq, Wqb, 4194304 / 4);
  cast_bf16_kernel<<<512, 256, 0, stream>>>(Wk, Wkb, 4194304 / 4);
  cast_bf16_kernel<<<512, 256, 0, stream>>>(Wv, Wvb, 4194304 / 4);
  cast_bf16_kernel<<<512, 256, 0, stream>>>(Wo, Wob, 4194304 / 4);

  dim3 gg(N / 128, M / 128);
  gemm_bt<0><<<gg, 256, 0, stream>>>(Xbf, Wqb, bq, Qb, M, N, Kd);
  gemm_bt<0><<<gg, 256, 0, stream>>>(Xbf, Wkb, bk, Kb, M, N, Kd);
  gemm_bt<0><<<gg, 256, 0, stream>>>(Xbf, Wvb, bv, Vb, M, N, Kd);

  rmsnorm_kernel<<<4096, 256, 0, stream>>>(Qb, qn);
  rmsnorm_kernel<<<4096, 256, 0, stream>>>(Kb, kn);

  flash_attn<<<1024, 256, 0, stream>>>(Qb, Kb, Vb, Ob);

  gemm_bt<1><<<gg, 256, 0, stream>>>(Ob, Wob, bo, (float*)d_out, M, N, Kd);
}